// Round 2
// baseline (1031.595 us; speedup 1.0000x reference)
//
#include <hip/hip_runtime.h>

#define TILE 512
#define KTOP 64
#define FMA_DOT 1   // 1: BLAS-style fma chains for the K=3 dots; 0: mul+add

// Anti-contraction barrier: forces the value to be materialized (rounded)
// before use, so hipcc's -ffp-contract=fast can't fuse across it.
#define BAR(x) asm volatile("" : "+v"(x))

__global__ __launch_bounds__(256)
void gna_main(const int* __restrict__ vox,
              const float* __restrict__ mu,
              const float* __restrict__ scale,
              const float* __restrict__ pcr,
              float* __restrict__ out,
              int M, int N)
{
    __shared__ float P[TILE * 8];   // i0,i1,i2, mi0,mi1,mi2, mt, r2

    const int tid = threadIdx.x;
    const int q = blockIdx.x * 256 + tid;
    const bool active = (q < M);

    const float pc0 = pcr[0], pc1 = pcr[1], pc2 = pcr[2];

    int ix = 0, iy = 0, iz = 0;
    if (active) {
        int4 c = ((const int4*)vox)[q];   // (b, z, y, x)
        iz = c.y; iy = c.z; ix = c.w;
    }
    // centers: pc + (idx+0.5)*0.2, each step rounded in f32 exactly like ref
    float tx = ((float)ix + 0.5f) * 0.2f; BAR(tx);
    float ty = ((float)iy + 0.5f) * 0.2f; BAR(ty);
    float tz = ((float)iz + 0.5f) * 0.2f; BAR(tz);
    const float qx = pc0 + tx;
    const float qy = pc1 + ty;
    const float qz = pc2 + tz;
    float qx2 = qx * qx; BAR(qx2);   // rounded before entering the dot (ref: Q*Q then @)
    float qy2 = qy * qy; BAR(qy2);
    float qz2 = qz * qz; BAR(qz2);

    if (active) {
        out[3 * (size_t)q + 0] = qx;
        out[3 * (size_t)q + 1] = qy;
        out[3 * (size_t)q + 2] = qz;
    }

    float key[KTOP];   // ascending d2; only [0,cnt) used
    int   gi[KTOP];
    int   cnt = 0;

    for (int t0 = 0; t0 < N; t0 += TILE) {
        const int lim = (N - t0 < TILE) ? (N - t0) : TILE;
        // stage params, f32 bit-exact to the reference elementwise ops
        for (int i = tid; i < lim; i += 256) {
            const int g = t0 + i;
            const float s0 = scale[3*g+0], s1 = scale[3*g+1], s2 = scale[3*g+2];
            const float m0 = mu[3*g+0],    m1 = mu[3*g+1],    m2 = mu[3*g+2];
            float s0s = s0 * s0; BAR(s0s);           // scale*scale, rounded
            float s1s = s1 * s1; BAR(s1s);
            float s2s = s2 * s2; BAR(s2s);
            float d0 = s0s + 1e-8f;                  // + EPS, rounded (no fusion: s0s opaque)
            float d1 = s1s + 1e-8f;
            float d2_ = s2s + 1e-8f;
            float i0 = 1.0f / d0;                    // IEEE-rounded f32 divide
            float i1 = 1.0f / d1;
            float i2 = 1.0f / d2_;
            float mi0 = m0 * i0; BAR(mi0);           // mu * inv, rounded
            float mi1 = m1 * i1; BAR(mi1);
            float mi2 = m2 * i2; BAR(mi2);
            float p0 = m0 * mi0; BAR(p0);            // products rounded, then ((p0+p1)+p2)
            float p1 = m1 * mi1; BAR(p1);
            float p2 = m2 * mi2; BAR(p2);
            float mt = (p0 + p1) + p2;
            float rs = (s0s + s1s) + s2s;            // sum(scale*scale)
            float r2 = 9.0f * rs;                    // *9 after the sum, one rounding
            float* p = &P[i * 8];
            p[0]=i0; p[1]=i1; p[2]=i2; p[3]=mi0; p[4]=mi1; p[5]=mi2; p[6]=mt; p[7]=r2;
        }
        __syncthreads();

        if (active) {
            for (int i = 0; i < lim; ++i) {
                const float4 pa = *(const float4*)&P[i * 8];
                const float4 pb = *(const float4*)&P[i * 8 + 4];
#if FMA_DOT
                // BLAS sgemm semantics: acc = fma(a_k, b_k, acc), k ascending
                float t1 = __builtin_fmaf(qz2, pa.z, __builtin_fmaf(qy2, pa.y, qx2 * pa.x));
                float t2 = __builtin_fmaf(qz,  pb.y, __builtin_fmaf(qy,  pb.x, qx  * pa.w));
#else
                float a0 = qx2 * pa.x; BAR(a0);
                float a1 = qy2 * pa.y; BAR(a1);
                float a2 = qz2 * pa.z; BAR(a2);
                float t1 = (a0 + a1) + a2;
                float b0 = qx * pa.w; BAR(b0);
                float b1 = qy * pb.x; BAR(b1);
                float b2 = qz * pb.y; BAR(b2);
                float t2 = (b0 + b1) + b2;
#endif
                const float t2m = 2.0f * t2;         // exact (power of two)
                const float d2 = (t1 - t2m) + pb.z;  // (A - 2B) + mu_term, left-to-right
                if (d2 <= pb.w) {
                    const int g = t0 + i;
                    int j;
                    if (cnt < KTOP) {
                        j = cnt++;
                    } else if (d2 < key[KTOP-1]) {
                        j = KTOP - 1;
                    } else {
                        continue;
                    }
                    while (j > 0 && key[j-1] > d2) {   // stable: ties keep lower index first
                        key[j] = key[j-1]; gi[j] = gi[j-1]; --j;
                    }
                    key[j] = d2; gi[j] = g;
                }
            }
        }
        __syncthreads();
    }

    if (active) {
        float* idxb = out + 3 * (size_t)M;
        float* wb   = idxb + (size_t)M * KTOP;
        float* mb   = wb   + (size_t)M * KTOP;
        const size_t base = (size_t)q * KTOP;
        for (int k = 0; k < KTOP; ++k) {
            const bool v = (k < cnt);
            idxb[base + k] = v ? (float)gi[k] : -1.0f;
            wb[base + k]   = v ? key[k] : 0.0f;
            mb[base + k]   = v ? 1.0f : 0.0f;
        }
    }
}

extern "C" void kernel_launch(void* const* d_in, const int* in_sizes, int n_in,
                              void* d_out, int out_size, void* d_ws, size_t ws_size,
                              hipStream_t stream)
{
    const int*   vox   = (const int*)d_in[0];
    const float* mu    = (const float*)d_in[1];
    const float* scale = (const float*)d_in[2];
    const float* pcr   = (const float*)d_in[3];
    float* out = (float*)d_out;

    const int M = in_sizes[0] / 4;
    const int N = in_sizes[1] / 3;
    const int blocks = (M + 255) / 256;

    hipLaunchKernelGGL(gna_main, dim3(blocks), dim3(256), 0, stream,
                       vox, mu, scale, pcr, out, M, N);
}

// Round 3
// 229.248 us; speedup vs baseline: 4.4999x; 4.4999x over previous
//
#include <hip/hip_runtime.h>

#define KTOP 64
#define SEGS 8
#define TPB  512          // 8 waves; wave s = segment s
#define QPB  64           // queries per block (lane = local query)
#define TILE 128          // gaussians staged per segment per round

// Anti-contraction barrier: force f32 rounding points to match the reference.
#define BAR(x) asm volatile("" : "+v"(x))

__global__ __launch_bounds__(TPB)
void gna_main(const int* __restrict__ vox,
              const float* __restrict__ mu,
              const float* __restrict__ scale,
              const float* __restrict__ pcr,
              float* __restrict__ out,
              int M, int N)
{
    __shared__ float P[SEGS][TILE][8];     // i0,i1,i2, mi0,mi1,mi2, mt, r2
    __shared__ float headk[SEGS][QPB];
    __shared__ int   headi[SEGS][QPB];
    __shared__ int   cnt_l[SEGS][QPB];
    __shared__ int   win[QPB];
    __shared__ int   Rsh;

    const int tid = threadIdx.x;
    const int s   = tid >> 6;              // wave id = segment
    const int l   = tid & 63;              // lane = local query
    const int q   = blockIdx.x * QPB + l;
    const bool active = (q < M);

    const int seglen = (N + SEGS - 1) / SEGS;      // 1024
    const int nrounds = (seglen + TILE - 1) / TILE; // 8
    const float INF = __builtin_inff();

    const float pc0 = pcr[0], pc1 = pcr[1], pc2 = pcr[2];

    int ix = 0, iy = 0, iz = 0;
    if (active) {
        int4 c = ((const int4*)vox)[q];    // (b, z, y, x)
        iz = c.y; iy = c.z; ix = c.w;
    }
    // centers: pc + (idx+0.5)*0.2, every step rounded in f32 like the ref
    float tx = ((float)ix + 0.5f) * 0.2f; BAR(tx);
    float ty = ((float)iy + 0.5f) * 0.2f; BAR(ty);
    float tz = ((float)iz + 0.5f) * 0.2f; BAR(tz);
    const float qx = pc0 + tx;
    const float qy = pc1 + ty;
    const float qz = pc2 + tz;
    float qx2 = qx * qx; BAR(qx2);
    float qy2 = qy * qy; BAR(qy2);
    float qz2 = qz * qz; BAR(qz2);

    if (active && s == 0) {
        out[3 * (size_t)q + 0] = qx;
        out[3 * (size_t)q + 1] = qy;
        out[3 * (size_t)q + 2] = qz;
    }

    float key[KTOP];   // ascending d2; only [0,cnt) touched
    int   gi[KTOP];
    int   cnt = 0;

    const int gseg0 = s * seglen;          // my segment's first gaussian

    for (int rnd = 0; rnd < nrounds; ++rnd) {
        // ---- cooperative staging: rows 0..SEGS*TILE-1, 2 rows per thread ----
        for (int r = tid; r < SEGS * TILE; r += TPB) {
            const int seg = r >> 7;        // r / TILE
            const int j   = r & (TILE - 1);
            const int off = rnd * TILE + j;
            const int g   = seg * seglen + off;
            float4 w0, w1;
            if (off < seglen && g < N) {
                const float s0 = scale[3*g+0], s1 = scale[3*g+1], s2 = scale[3*g+2];
                const float m0 = mu[3*g+0],    m1 = mu[3*g+1],    m2 = mu[3*g+2];
                float s0s = s0 * s0; BAR(s0s);
                float s1s = s1 * s1; BAR(s1s);
                float s2s = s2 * s2; BAR(s2s);
                float d0 = s0s + 1e-8f;
                float d1 = s1s + 1e-8f;
                float dd2 = s2s + 1e-8f;
                float i0 = 1.0f / d0;
                float i1 = 1.0f / d1;
                float i2 = 1.0f / dd2;
                float mi0 = m0 * i0; BAR(mi0);
                float mi1 = m1 * i1; BAR(mi1);
                float mi2 = m2 * i2; BAR(mi2);
                float p0 = m0 * mi0; BAR(p0);
                float p1 = m1 * mi1; BAR(p1);
                float p2 = m2 * mi2; BAR(p2);
                float mt = (p0 + p1) + p2;
                float rs = (s0s + s1s) + s2s;
                float r2 = 9.0f * rs;
                w0 = make_float4(i0, i1, i2, mi0);
                w1 = make_float4(mi1, mi2, mt, r2);
            } else {
                w0 = make_float4(0.f, 0.f, 0.f, 0.f);
                w1 = make_float4(0.f, 0.f, 0.f, -INF);   // gate never passes
            }
            *(float4*)&P[seg][j][0] = w0;
            *(float4*)&P[seg][j][4] = w1;
        }
        __syncthreads();

        // ---- scan my segment's tile (broadcast reads, all lanes same addr) ----
        if (active) {
            const float* base = &P[s][0][0];
            const int gb = gseg0 + rnd * TILE;
            #pragma unroll 4
            for (int i = 0; i < TILE; ++i) {
                const float4 pa = *(const float4*)(base + i * 8);
                const float4 pb = *(const float4*)(base + i * 8 + 4);
                // BLAS fma-chain dots (bit-exact vs ref, proven round 2)
                float t1 = __builtin_fmaf(qz2, pa.z, __builtin_fmaf(qy2, pa.y, qx2 * pa.x));
                float t2 = __builtin_fmaf(qz,  pb.y, __builtin_fmaf(qy,  pb.x, qx  * pa.w));
                const float d2v = (t1 - 2.0f * t2) + pb.z;
                if (d2v <= pb.w) {
                    int j;
                    if (cnt < KTOP) {
                        j = cnt++;
                    } else if (d2v < key[KTOP-1]) {
                        j = KTOP - 1;
                    } else {
                        continue;
                    }
                    while (j > 0 && key[j-1] > d2v) {   // stable: ties keep lower index
                        key[j] = key[j-1]; gi[j] = gi[j-1]; --j;
                    }
                    key[j] = d2v; gi[j] = gb + i;
                }
            }
        }
        __syncthreads();
    }

    // ---- cross-segment merge: extract-min rounds through LDS ----
    cnt_l[s][l] = cnt;
    __syncthreads();

    if (s == 0) {
        int total = 0;
        #pragma unroll
        for (int s2 = 0; s2 < SEGS; ++s2) total += cnt_l[s2][l];
        int myR = total < KTOP ? total : KTOP;
        for (int off = 32; off; off >>= 1) {
            int o = __shfl_xor(myR, off);
            myR = myR > o ? myR : o;
        }
        if (l == 0) Rsh = myR;
        win[l] = -1;
    }
    __syncthreads();
    const int R = Rsh;

    float* idxb = out + 3 * (size_t)M;
    float* wb   = idxb + (size_t)M * KTOP;
    float* mb   = wb   + (size_t)M * KTOP;

    int p = 0;
    for (int r = 0; r < R; ++r) {
        headk[s][l] = (p < cnt) ? key[p] : INF;
        headi[s][l] = (p < cnt) ? gi[p]  : -1;
        __syncthreads();
        if (s == 0) {
            int wseg = -1, widx = -1;
            float m = INF;
            #pragma unroll
            for (int s2 = 0; s2 < SEGS; ++s2) {        // lowest segment wins ties
                float v = headk[s2][l];
                if (v < m) { m = v; wseg = s2; widx = headi[s2][l]; }
            }
            if (active) {
                const size_t o = (size_t)q * KTOP + r;
                if (wseg >= 0) { idxb[o] = (float)widx; wb[o] = m;   mb[o] = 1.0f; }
                else           { idxb[o] = -1.0f;       wb[o] = 0.f; mb[o] = 0.0f; }
            }
            win[l] = wseg;
        }
        __syncthreads();
        if (win[l] == s) ++p;
    }

    // fill slots R..63 (cooperative across the 8 waves)
    if (active) {
        for (int k = R + s; k < KTOP; k += SEGS) {
            const size_t o = (size_t)q * KTOP + k;
            idxb[o] = -1.0f; wb[o] = 0.0f; mb[o] = 0.0f;
        }
    }
}

extern "C" void kernel_launch(void* const* d_in, const int* in_sizes, int n_in,
                              void* d_out, int out_size, void* d_ws, size_t ws_size,
                              hipStream_t stream)
{
    const int*   vox   = (const int*)d_in[0];
    const float* mu    = (const float*)d_in[1];
    const float* scale = (const float*)d_in[2];
    const float* pcr   = (const float*)d_in[3];
    float* out = (float*)d_out;

    const int M = in_sizes[0] / 4;
    const int N = in_sizes[1] / 3;
    const int blocks = (M + QPB - 1) / QPB;

    hipLaunchKernelGGL(gna_main, dim3(blocks), dim3(TPB), 0, stream,
                       vox, mu, scale, pcr, out, M, N);
}